// Round 1
// baseline (577.647 us; speedup 1.0000x reference)
//
#include <hip/hip_runtime.h>
#include <hip/hip_bf16.h>

#define NN 100000
#define DD 64
#define EE 400000
#define TT 5

typedef __bf16 bf16x8 __attribute__((ext_vector_type(8)));
typedef float  f32x4  __attribute__((ext_vector_type(4)));

// ws layout (bytes)
#define OFF_XBF 0u                    // N*D ushort = 12,800,000 B
#define OFF_WT  12800000u             // T*64*128 ushort = 81,920 B
#define OFF_CNT 12881920u             // T*N u32 = 2,000,000 B
#define OFF_WGT 14881920u             // T f32

__device__ __forceinline__ unsigned short f2bf(float f) {
    union { float f; unsigned u; } v; v.f = f;
    unsigned u = v.u;
    return (unsigned short)((u + 0x7FFFu + ((u >> 16) & 1u)) >> 16);  // RNE
}

// ---------------- Phase 1: init / convert ----------------
__global__ void k_init(const float* __restrict__ x, const float* __restrict__ W,
                       const float* __restrict__ ea,
                       unsigned short* __restrict__ xbf, unsigned short* __restrict__ wT,
                       unsigned* __restrict__ counts, float* __restrict__ wgt,
                       float* __restrict__ out) {
    int i = blockIdx.x * blockDim.x + threadIdx.x;   // grid covers N*D exactly
    if (i < NN * DD) {
        out[i] = 0.0f;
        xbf[i] = f2bf(x[i]);
    }
    if (i < TT * NN) counts[i] = 0u;
    if (i < TT * 128 * 64) {
        int t = i >> 13;          // /8192
        int rem = i & 8191;
        int d = rem >> 7;         // /128
        int k = rem & 127;
        wT[i] = f2bf(W[t * 8192 + k * 64 + d]);   // wT[t][d][k] = W[t][k][d]
    }
    if (i == 0) {
        float m = -1e30f;
        for (int t = 0; t < TT; t++) m = fmaxf(m, ea[t]);
        float e[TT]; float s = 0.0f;
        for (int t = 0; t < TT; t++) { e[t] = __expf(ea[t] - m); s += e[t]; }
        for (int t = 0; t < TT; t++) wgt[t] = e[t] / s;
    }
}

// ---------------- Phase 2: per-(t,src) degree ----------------
__global__ void k_count(const int* __restrict__ edges, unsigned* __restrict__ counts) {
    int i = blockIdx.x * blockDim.x + threadIdx.x;
    if (i >= TT * EE) return;
    int t = i / EE;
    int e = i - t * EE;
    int s = edges[(size_t)t * 2 * EE + e];          // src row
    atomicAdd(&counts[t * NN + s], 1u);
}

// ---------------- Phase 3: gather -> MFMA -> fused scatter-mean ----------------
__global__ __launch_bounds__(256) void k_edge(
    const unsigned short* __restrict__ xbf, const unsigned short* __restrict__ wT,
    const float* __restrict__ b, const int* __restrict__ edges,
    const unsigned* __restrict__ counts, const float* __restrict__ wgt,
    float* __restrict__ out) {
    const int t  = blockIdx.y;
    const int e0 = blockIdx.x * 128;

    __shared__ unsigned short Ab[128][136];   // feats tile, +8 pad (16B) per row
    __shared__ unsigned short Bb[64][136];    // W_t^T [d][k]
    __shared__ float scale_s[128];
    __shared__ int   src_s[128];

    const int tid = threadIdx.x;

    // stage B: W_t^T is 64x128 bf16 contiguous in ws
    {
        const unsigned short* src = wT + (size_t)t * 8192;
        int d = tid >> 2, seg = tid & 3;                       // 64B per thread
        const float4* g = reinterpret_cast<const float4*>(src + d * 128 + seg * 32);
        float4* l = reinterpret_cast<float4*>(&Bb[d][seg * 32]);
#pragma unroll
        for (int c = 0; c < 4; c++) l[c] = g[c];
    }
    // stage A: gather x rows (bf16, 128B each); thread pair per edge
    {
        int e = tid >> 1, half = tid & 1;
        int idx = edges[(size_t)t * 2 * EE + (size_t)half * EE + e0 + e];
        const float4* g = reinterpret_cast<const float4*>(xbf + (size_t)idx * 64);
        float4* l = reinterpret_cast<float4*>(&Ab[e][half * 64]);
#pragma unroll
        for (int c = 0; c < 8; c++) l[c] = g[c];
        if (half == 0) {
            src_s[e] = idx;
            unsigned c = counts[t * NN + idx];
            scale_s[e] = wgt[t] / (float)(c ? c : 1u);
        }
    }
    __syncthreads();

    const int wv = tid >> 6, lane = tid & 63;
    const int m16 = lane & 15, quad = lane >> 4;

    f32x4 acc[2][4];
#pragma unroll
    for (int tm = 0; tm < 2; tm++)
#pragma unroll
        for (int tn = 0; tn < 4; tn++)
            acc[tm][tn] = (f32x4){0.f, 0.f, 0.f, 0.f};

#pragma unroll
    for (int kk = 0; kk < 128; kk += 32) {
        const int kb = kk + quad * 8;
        bf16x8 af[2], bfr[4];
#pragma unroll
        for (int tm = 0; tm < 2; tm++)
            af[tm] = *reinterpret_cast<const bf16x8*>(&Ab[wv * 32 + tm * 16 + m16][kb]);
#pragma unroll
        for (int tn = 0; tn < 4; tn++)
            bfr[tn] = *reinterpret_cast<const bf16x8*>(&Bb[tn * 16 + m16][kb]);
#pragma unroll
        for (int tm = 0; tm < 2; tm++)
#pragma unroll
            for (int tn = 0; tn < 4; tn++)
                acc[tm][tn] = __builtin_amdgcn_mfma_f32_16x16x32_bf16(
                    af[tm], bfr[tn], acc[tm][tn], 0, 0, 0);
    }

    // epilogue: bias + relu + (w_t / count) scale + scatter
    float bias[4];
#pragma unroll
    for (int tn = 0; tn < 4; tn++) bias[tn] = b[t * 64 + tn * 16 + m16];

#pragma unroll
    for (int tm = 0; tm < 2; tm++) {
#pragma unroll
        for (int r = 0; r < 4; r++) {
            const int eloc = wv * 32 + tm * 16 + quad * 4 + r;
            const float s = scale_s[eloc];
            float* orow = out + (size_t)src_s[eloc] * 64;
#pragma unroll
            for (int tn = 0; tn < 4; tn++) {
                float v = acc[tm][tn][r] + bias[tn];
                v = v > 0.f ? v : 0.f;
                atomicAdd(orow + tn * 16 + m16, v * s);
            }
        }
    }
}

extern "C" void kernel_launch(void* const* d_in, const int* in_sizes, int n_in,
                              void* d_out, int out_size, void* d_ws, size_t ws_size,
                              hipStream_t stream) {
    const float* x     = (const float*)d_in[0];
    const float* W     = (const float*)d_in[1];
    const float* b     = (const float*)d_in[2];
    const float* ea    = (const float*)d_in[3];
    const int*   edges = (const int*)d_in[4];
    float* out = (float*)d_out;

    char* ws = (char*)d_ws;
    unsigned short* xbf = (unsigned short*)(ws + OFF_XBF);
    unsigned short* wT  = (unsigned short*)(ws + OFF_WT);
    unsigned* counts    = (unsigned*)(ws + OFF_CNT);
    float* wgt          = (float*)(ws + OFF_WGT);

    // Phase 1: 6.4M threads covers out-zero, x->bf16, counts-zero, W^T, softmax
    k_init<<<(NN * DD) / 256, 256, 0, stream>>>(x, W, ea, xbf, wT, counts, wgt, out);

    // Phase 2: degree counts
    k_count<<<(TT * EE + 255) / 256, 256, 0, stream>>>(edges, counts);

    // Phase 3: MFMA gather-GEMM-scatter; one block = 1 t x 128 edges
    dim3 grid(EE / 128, TT);
    k_edge<<<grid, 256, 0, stream>>>(xbf, wT, b, edges, counts, wgt, out);
}